// Round 1
// baseline (392.580 us; speedup 1.0000x reference)
//
#include <hip/hip_runtime.h>
#include <hip/hip_bf16.h>

#define NSEQ   192
#define NPAIRS 18336          // 192*191/2
#define HPAD   160            // H=150 padded to 160
#define PADV   -1000.0f
#define NEGINF -1.0e30f

typedef __bf16 bf16x8 __attribute__((ext_vector_type(8)));
typedef float  f32x4  __attribute__((ext_vector_type(4)));

// ---------------------------------------------------------------------------
// P1: repack W1c (rows 1536..2303 of W1) and W2 into bf16 MFMA B-fragment
// order: chunk (kk,ct) is 64 lanes x 8 bf16, lane l holds B[kk*32+(l>>4)*8+e,
// ct*16+(l&15)]. One coalesced 16B load per fragment in the GEMM.
// ---------------------------------------------------------------------------
__global__ __launch_bounds__(256) void prep_pack(const float* __restrict__ W1,
                                                 const float* __restrict__ W2,
                                                 __bf16* __restrict__ W1p,
                                                 __bf16* __restrict__ W2p) {
  int idx = blockIdx.x * 256 + threadIdx.x;   // grid chosen so idx < 122880
  {
    int e = idx & 7, l = (idx >> 3) & 63, t = idx >> 9;
    int ct = t % 10, kk = t / 10;             // kk in 0..23
    int k = kk * 32 + ((l >> 4) << 3) + e;    // 0..767
    int h = ct * 16 + (l & 15);               // 0..159
    float v = (h < 150) ? W1[(size_t)(1536 + k) * 150 + h] : 0.f;
    W1p[idx] = (__bf16)v;
  }
  if (idx < 25600) {                          // W2 pack: kk in 0..4
    int e = idx & 7, l = (idx >> 3) & 63, t = idx >> 9;
    int ct = t % 10, kk = t / 10;
    int k = kk * 32 + ((l >> 4) << 3) + e;    // 0..159
    int h = ct * 16 + (l & 15);
    float v = (k < 150 && h < 150) ? W2[(size_t)k * 150 + h] : 0.f;
    W2p[idx] = (__bf16)v;
  }
}

// ---------------------------------------------------------------------------
// P2: A1[b,n,:] = E[b,n]@W1a + b1 ; A2[b,n,:] = E[b,n]@W1b   (f32, HPAD cols,
// pad cols = 0). LDS-tiled so W1 columns are read coalesced and reused x16.
// ---------------------------------------------------------------------------
__global__ __launch_bounds__(256) void prep_A12(const float* __restrict__ E,
                                                const float* __restrict__ W1,
                                                const float* __restrict__ b1,
                                                float* __restrict__ A1,
                                                float* __restrict__ A2) {
  __shared__ float Wl[32][160];
  __shared__ float El[16][33];
  int sel = blockIdx.x & 1;
  int bn0 = (blockIdx.x >> 1) * 16;
  int tid = threadIdx.x;
  int r = tid >> 4, c = tid & 15;
  float acc[10];
#pragma unroll
  for (int u = 0; u < 10; ++u) acc[u] = 0.f;
  for (int d0 = 0; d0 < 768; d0 += 32) {
    __syncthreads();
    for (int t = tid; t < 32 * 160; t += 256) {
      int dd = t / 160, h = t % 160;
      Wl[dd][h] = (h < 150) ? W1[(size_t)(sel * 768 + d0 + dd) * 150 + h] : 0.f;
    }
    for (int t = tid; t < 512; t += 256) {
      int rr = t >> 5, dd = t & 31;
      El[rr][dd] = E[(size_t)(bn0 + rr) * 768 + d0 + dd];
    }
    __syncthreads();
#pragma unroll
    for (int dd = 0; dd < 32; ++dd) {
      float e = El[r][dd];
#pragma unroll
      for (int u = 0; u < 10; ++u) acc[u] += e * Wl[dd][c + 16 * u];
    }
  }
  float* dst = sel ? A2 : A1;
#pragma unroll
  for (int u = 0; u < 10; ++u) {
    int h = c + 16 * u;
    float v = acc[u];
    if (h >= 150) v = 0.f;
    else if (sel == 0) v += b1[h];
    dst[(size_t)(bn0 + r) * HPAD + h] = v;
  }
}

// ---------------------------------------------------------------------------
// Main kernel: 64 pairs per block, 4 waves x 16 rows. Per pair row:
//   term3 = (e_i .* e_j) @ W1c   via MFMA 16x16x32 bf16, A-frags built in regs
//   h1 = relu(term3 + A1[i] + A2[j])        -> LDS bf16
//   h2 = relu(h1 @ W2 + b2) ; s = h2 @ W3 + b3 -> scatter to out[b,i,j]
// ---------------------------------------------------------------------------
__global__ __launch_bounds__(256) void pair_mlp(
    const float* __restrict__ E, const float* __restrict__ A1,
    const float* __restrict__ A2, const __bf16* __restrict__ W1p,
    const __bf16* __restrict__ W2p, const float* __restrict__ b2,
    const float* __restrict__ W3, const float* __restrict__ b3,
    float* __restrict__ out) {
  __shared__ int bi_s[64], bj_s[64], js_s[64];
  __shared__ __bf16 h1s[4][16][168];   // row pad 168 (336B) -> conflict-free-ish
  int tid = threadIdx.x;
  int w = tid >> 6, l = tid & 63;
  int m = l & 15, kg = l >> 4;

  if (tid < 64) {  // decode pair index -> (b, i, j)
    int g = blockIdx.x * 64 + tid;
    int b = g / NPAIRS;
    int p = g - b * NPAIRS;
    float f = sqrtf(8.0f * (float)p + 1.0f);
    int i = (int)((1.0f + f) * 0.5f);
    while (i * (i - 1) / 2 > p) --i;
    while ((i + 1) * i / 2 <= p) ++i;
    int j = p - i * (i - 1) / 2;
    bi_s[tid] = b * NSEQ + i;
    bj_s[tid] = b * NSEQ + j;
    js_s[tid] = j;
  }
  __syncthreads();

  int row = w * 16 + m;
  const float* ei = E + (size_t)bi_s[row] * 768;
  const float* ej = E + (size_t)bj_s[row] * 768;

  f32x4 acc[10];
#pragma unroll
  for (int u = 0; u < 10; ++u) acc[u] = (f32x4){0.f, 0.f, 0.f, 0.f};

  for (int kk = 0; kk < 24; ++kk) {
    int k = kk * 32 + kg * 8;
    f32x4 x0 = *(const f32x4*)(ei + k);
    f32x4 x1 = *(const f32x4*)(ei + k + 4);
    f32x4 y0 = *(const f32x4*)(ej + k);
    f32x4 y1 = *(const f32x4*)(ej + k + 4);
    bf16x8 af;
#pragma unroll
    for (int e = 0; e < 4; ++e) {
      af[e]     = (__bf16)(x0[e] * y0[e]);
      af[e + 4] = (__bf16)(x1[e] * y1[e]);
    }
    const bf16x8* wp = (const bf16x8*)W1p + (size_t)(kk * 10) * 64 + l;
#pragma unroll
    for (int ct = 0; ct < 10; ++ct)
      acc[ct] = __builtin_amdgcn_mfma_f32_16x16x32_bf16(af, wp[ct * 64], acc[ct], 0, 0, 0);
  }

  // epilogue 1: h1 = relu(term3 + A1[i] + A2[j]) -> LDS bf16
#pragma unroll
  for (int r = 0; r < 4; ++r) {
    int rr = kg * 4 + r;   // C/D layout: row = (l>>4)*4 + reg, col = l&15
    const float* a1p = A1 + (size_t)bi_s[w * 16 + rr] * HPAD;
    const float* a2p = A2 + (size_t)bj_s[w * 16 + rr] * HPAD;
#pragma unroll
    for (int ct = 0; ct < 10; ++ct) {
      int h = ct * 16 + m;
      float v = acc[ct][r] + a1p[h] + a2p[h];
      h1s[w][rr][h] = (__bf16)fmaxf(v, 0.f);
    }
  }
  __syncthreads();

  // GEMM2: h2 = h1 @ W2  (K = 160, 5 MFMA K-steps)
  f32x4 acc2[10];
#pragma unroll
  for (int u = 0; u < 10; ++u) acc2[u] = (f32x4){0.f, 0.f, 0.f, 0.f};
#pragma unroll
  for (int kk = 0; kk < 5; ++kk) {
    bf16x8 a2f = *(const bf16x8*)(&h1s[w][m][kk * 32 + kg * 8]);
    const bf16x8* wp = (const bf16x8*)W2p + (size_t)(kk * 10) * 64 + l;
#pragma unroll
    for (int ct = 0; ct < 10; ++ct)
      acc2[ct] = __builtin_amdgcn_mfma_f32_16x16x32_bf16(a2f, wp[ct * 64], acc2[ct], 0, 0, 0);
  }

  // epilogue 2: s = relu(h2 + b2) @ W3 + b3, reduce over the 16 col-lanes
  float part[4] = {0.f, 0.f, 0.f, 0.f};
#pragma unroll
  for (int ct = 0; ct < 10; ++ct) {
    int h = ct * 16 + m;
    float bb = (h < 150) ? b2[h] : 0.f;
    float w3 = (h < 150) ? W3[h] : 0.f;
#pragma unroll
    for (int r = 0; r < 4; ++r)
      part[r] += fmaxf(acc2[ct][r] + bb, 0.f) * w3;
  }
#pragma unroll
  for (int off = 8; off >= 1; off >>= 1) {
#pragma unroll
    for (int r = 0; r < 4; ++r) part[r] += __shfl_xor(part[r], off, 16);
  }
  float b3v = b3[0];
#pragma unroll
  for (int r = 0; r < 4; ++r) {
    if (m == r) {
      int rr = kg * 4 + r;
      out[(size_t)bi_s[w * 16 + rr] * NSEQ + js_s[w * 16 + rr]] = part[r] + b3v;
    }
  }
}

// ---------------------------------------------------------------------------
// In-place masked softmax per (b,i) row: entries j<i are s, j==i is 0 (never
// written by pair_mlp), j>i -> PAD. One wave per row, 3 elems/lane.
// ---------------------------------------------------------------------------
__global__ __launch_bounds__(64) void softmax_rows(float* __restrict__ out) {
  int blk = blockIdx.x;           // 0..1535 = b*192+i
  int i = blk % NSEQ;
  size_t base = (size_t)blk * NSEQ;
  int l = threadIdx.x;
  float v[3];
  float mx = NEGINF;
#pragma unroll
  for (int t = 0; t < 3; ++t) {
    int j = l + 64 * t;
    float x = (j < i) ? out[base + j] : (j == i ? 0.f : NEGINF);
    v[t] = x;
    mx = fmaxf(mx, x);
  }
#pragma unroll
  for (int off = 32; off >= 1; off >>= 1) mx = fmaxf(mx, __shfl_xor(mx, off, 64));
  float s = 0.f;
#pragma unroll
  for (int t = 0; t < 3; ++t) s += __expf(v[t] - mx);  // exp(NEGINF-mx)=0
#pragma unroll
  for (int off = 32; off >= 1; off >>= 1) s += __shfl_xor(s, off, 64);
  float inv = 1.0f / s;
#pragma unroll
  for (int t = 0; t < 3; ++t) {
    int j = l + 64 * t;
    out[base + j] = (j <= i) ? __expf(v[t] - mx) * inv : PADV;
  }
}

// ---------------------------------------------------------------------------
extern "C" void kernel_launch(void* const* d_in, const int* in_sizes, int n_in,
                              void* d_out, int out_size, void* d_ws, size_t ws_size,
                              hipStream_t stream) {
  const float* E  = (const float*)d_in[0];
  const float* W1 = (const float*)d_in[1];
  const float* b1 = (const float*)d_in[2];
  const float* W2 = (const float*)d_in[3];
  const float* b2 = (const float*)d_in[4];
  const float* W3 = (const float*)d_in[5];
  const float* b3 = (const float*)d_in[6];
  float* out = (float*)d_out;

  char* ws = (char*)d_ws;
  float*  A1  = (float*)(ws);                  //  983040 B (1536*160 f32)
  float*  A2  = (float*)(ws + 983040);         //  983040 B
  __bf16* W1p = (__bf16*)(ws + 1966080);       //  245760 B (24*10*64*8 bf16)
  __bf16* W2p = (__bf16*)(ws + 2211840);       //   51200 B (5*10*64*8 bf16)

  prep_pack<<<480, 256, 0, stream>>>(W1, W2, W1p, W2p);     // 480*256==122880
  prep_A12<<<192, 256, 0, stream>>>(E, W1, b1, A1, A2);
  pair_mlp<<<2292, 256, 0, stream>>>(E, A1, A2, W1p, W2p, b2, W3, b3, out);
  softmax_rows<<<1536, 64, 0, stream>>>(out);
}

// Round 2
// 232.593 us; speedup vs baseline: 1.6878x; 1.6878x over previous
//
#include <hip/hip_runtime.h>
#include <hip/hip_bf16.h>

#define NSEQ   192
#define NPAIRS 18336          // 192*191/2
#define TOTPAIRS 146688       // 8 * 18336
#define PADV   -1000.0f
#define NEGINF -1.0e30f

typedef __bf16 bf16x8 __attribute__((ext_vector_type(8)));
typedef float  f32x4  __attribute__((ext_vector_type(4)));

// ---------------------------------------------------------------------------
// prep_pack: repack weights into bf16 MFMA B-fragment order.
//   frag (kk,ct): lane l elem e holds B[kk*32+(l>>4)*8+e][ct*16+(l&15)]
// Region 1: W1ab = [W1a | W1b] cols 0..319  (24 kk x 20 ct)   245760 elems
// Region 2: W1c  (rows 1536.. of W1)        (24 kk x 10 ct)   122880 elems
// Region 3: W2                              ( 5 kk x 10 ct)    25600 elems
// ---------------------------------------------------------------------------
__global__ __launch_bounds__(256) void prep_pack(const float* __restrict__ W1,
                                                 const float* __restrict__ W2,
                                                 __bf16* __restrict__ W1abp,
                                                 __bf16* __restrict__ W1cp,
                                                 __bf16* __restrict__ W2p) {
  int idx = blockIdx.x * 256 + threadIdx.x;   // grid: 1540*256 == 394240 exact
  if (idx < 245760) {
    int e = idx & 7, l = (idx >> 3) & 63, t = idx >> 9;
    int ct = t % 20, kk = t / 20;             // kk 0..23
    int k = kk * 32 + ((l >> 4) << 3) + e;    // 0..767
    int hp = ct * 16 + (l & 15);              // 0..319
    int col = (hp < 160) ? hp : hp - 160;
    int rbase = (hp < 160) ? 0 : 768;
    float v = (col < 150) ? W1[(size_t)(rbase + k) * 150 + col] : 0.f;
    W1abp[idx] = (__bf16)v;
  } else if (idx < 245760 + 122880) {
    int j = idx - 245760;
    int e = j & 7, l = (j >> 3) & 63, t = j >> 9;
    int ct = t % 10, kk = t / 10;             // kk 0..23
    int k = kk * 32 + ((l >> 4) << 3) + e;
    int h = ct * 16 + (l & 15);
    float v = (h < 150) ? W1[(size_t)(1536 + k) * 150 + h] : 0.f;
    W1cp[j] = (__bf16)v;
  } else {
    int j = idx - 368640;                     // < 25600
    int e = j & 7, l = (j >> 3) & 63, t = j >> 9;
    int ct = t % 10, kk = t / 10;             // kk 0..4
    int k = kk * 32 + ((l >> 4) << 3) + e;    // 0..159
    int h = ct * 16 + (l & 15);
    float v = (k < 150 && h < 150) ? W2[(size_t)k * 150 + h] : 0.f;
    W2p[j] = (__bf16)v;
  }
}

// ---------------------------------------------------------------------------
// prep_gemm: A12[1536][320] += E @ [W1a|W1b], K split 8 ways (f32 atomics).
// Block: M=16 rows (mt), K-chunk c of 96; wave w covers ct [5w,5w+5).
// A12 must be zeroed before (hipMemsetAsync). b1 is added in pair_mlp.
// ---------------------------------------------------------------------------
__global__ __launch_bounds__(256) void prep_gemm(const float* __restrict__ E,
                                                 const __bf16* __restrict__ W1abp,
                                                 float* __restrict__ A12) {
  int tid = threadIdx.x;
  int w = tid >> 6, l = tid & 63, m = l & 15, kg = l >> 4;
  int mt = blockIdx.x >> 3;                   // 0..95
  int c  = blockIdx.x & 7;                    // K-chunk 0..7
  const float* ep = E + (size_t)(mt * 16 + m) * 768 + c * 96;

  f32x4 acc[5];
#pragma unroll
  for (int u = 0; u < 5; ++u) acc[u] = (f32x4){0.f, 0.f, 0.f, 0.f};

#pragma unroll
  for (int kk = 0; kk < 3; ++kk) {
    int k = kk * 32 + kg * 8;
    f32x4 x0 = *(const f32x4*)(ep + k);
    f32x4 x1 = *(const f32x4*)(ep + k + 4);
    bf16x8 af;
#pragma unroll
    for (int e = 0; e < 4; ++e) { af[e] = (__bf16)x0[e]; af[e + 4] = (__bf16)x1[e]; }
    const bf16x8* wp = (const bf16x8*)W1abp + (size_t)(((c * 3 + kk) * 20) + w * 5) * 64 + l;
#pragma unroll
    for (int u = 0; u < 5; ++u)
      acc[u] = __builtin_amdgcn_mfma_f32_16x16x32_bf16(af, wp[u * 64], acc[u], 0, 0, 0);
  }
#pragma unroll
  for (int u = 0; u < 5; ++u)
#pragma unroll
    for (int r = 0; r < 4; ++r)
      atomicAdd(&A12[(size_t)(mt * 16 + kg * 4 + r) * 320 + (w * 5 + u) * 16 + m], acc[u][r]);
}

// ---------------------------------------------------------------------------
// pair_mlp: 128 pairs/block, 4 waves, 32 rows/wave (2 row-groups share each
// B-fragment). acc initialized with A1[i]+A2[j]+b1 so layer-1 bias/linear
// terms load before the K-loop and hide under it. h1s is wave-private (no
// block barriers in the main body).
// ---------------------------------------------------------------------------
__global__ __launch_bounds__(256) void pair_mlp(
    const float* __restrict__ E, const float* __restrict__ A12,
    const __bf16* __restrict__ W1cp, const __bf16* __restrict__ W2p,
    const float* __restrict__ b1, const float* __restrict__ b2,
    const float* __restrict__ W3, const float* __restrict__ b3,
    float* __restrict__ out) {
  __shared__ int bi_s[128], bj_s[128], js_s[128];
  __shared__ __bf16 h1s[4][16][168];
  int tid = threadIdx.x;
  int w = tid >> 6, l = tid & 63;
  int m = l & 15, kg = l >> 4;

  if (tid < 128) {  // decode pair index -> (b, i, j)
    int g = blockIdx.x * 128 + tid;           // grid exact: 1146*128 == 146688
    int b = g / NPAIRS;
    int p = g - b * NPAIRS;
    float f = sqrtf(8.0f * (float)p + 1.0f);
    int i = (int)((1.0f + f) * 0.5f);
    while (i * (i - 1) / 2 > p) --i;
    while ((i + 1) * i / 2 <= p) ++i;
    int j = p - i * (i - 1) / 2;
    bi_s[tid] = b * NSEQ + i;
    bj_s[tid] = b * NSEQ + j;
    js_s[tid] = j;
  }
  __syncthreads();

  const float* ei0 = E + (size_t)bi_s[w * 32 + m] * 768;
  const float* ej0 = E + (size_t)bj_s[w * 32 + m] * 768;
  const float* ei1 = E + (size_t)bi_s[w * 32 + 16 + m] * 768;
  const float* ej1 = E + (size_t)bj_s[w * 32 + 16 + m] * 768;

  // init acc with A1[i] + A2[j] + b1 at (row = kg*4+r, h = ct*16+m)
  f32x4 acc[2][10];
#pragma unroll
  for (int rg = 0; rg < 2; ++rg)
#pragma unroll
    for (int r = 0; r < 4; ++r) {
      int row = w * 32 + rg * 16 + kg * 4 + r;
      const float* a1p = A12 + (size_t)bi_s[row] * 320;
      const float* a2p = A12 + (size_t)bj_s[row] * 320 + 160;
#pragma unroll
      for (int ct = 0; ct < 10; ++ct) {
        int h = ct * 16 + m;
        float bb = (h < 150) ? b1[h] : 0.f;
        acc[rg][ct][r] = a1p[h] + a2p[h] + bb;
      }
    }

  for (int kk = 0; kk < 24; ++kk) {
    int k = kk * 32 + kg * 8;
    f32x4 x0 = *(const f32x4*)(ei0 + k);
    f32x4 x1 = *(const f32x4*)(ei0 + k + 4);
    f32x4 y0 = *(const f32x4*)(ej0 + k);
    f32x4 y1 = *(const f32x4*)(ej0 + k + 4);
    f32x4 u0 = *(const f32x4*)(ei1 + k);
    f32x4 u1 = *(const f32x4*)(ei1 + k + 4);
    f32x4 v0 = *(const f32x4*)(ej1 + k);
    f32x4 v1 = *(const f32x4*)(ej1 + k + 4);
    bf16x8 a0, a1;
#pragma unroll
    for (int e = 0; e < 4; ++e) {
      a0[e]     = (__bf16)(x0[e] * y0[e]);
      a0[e + 4] = (__bf16)(x1[e] * y1[e]);
      a1[e]     = (__bf16)(u0[e] * v0[e]);
      a1[e + 4] = (__bf16)(u1[e] * v1[e]);
    }
    const bf16x8* wp = (const bf16x8*)W1cp + (size_t)(kk * 10) * 64 + l;
    bf16x8 wfr[10];
#pragma unroll
    for (int ct = 0; ct < 10; ++ct) wfr[ct] = wp[ct * 64];
#pragma unroll
    for (int ct = 0; ct < 10; ++ct) {
      acc[0][ct] = __builtin_amdgcn_mfma_f32_16x16x32_bf16(a0, wfr[ct], acc[0][ct], 0, 0, 0);
      acc[1][ct] = __builtin_amdgcn_mfma_f32_16x16x32_bf16(a1, wfr[ct], acc[1][ct], 0, 0, 0);
    }
  }

  float b3v = b3[0];
#pragma unroll
  for (int rg = 0; rg < 2; ++rg) {
    // epilogue 1: relu -> wave-private LDS (no block barrier needed)
#pragma unroll
    for (int r = 0; r < 4; ++r) {
      int rr = kg * 4 + r;
#pragma unroll
      for (int ct = 0; ct < 10; ++ct)
        h1s[w][rr][ct * 16 + m] = (__bf16)fmaxf(acc[rg][ct][r], 0.f);
    }

    // GEMM2: h2 = h1 @ W2  (K = 160, 5 MFMA K-steps)
    f32x4 acc2[10];
#pragma unroll
    for (int u = 0; u < 10; ++u) acc2[u] = (f32x4){0.f, 0.f, 0.f, 0.f};
#pragma unroll
    for (int kk = 0; kk < 5; ++kk) {
      bf16x8 a2f = *(const bf16x8*)(&h1s[w][m][kk * 32 + kg * 8]);
      const bf16x8* wp = (const bf16x8*)W2p + (size_t)(kk * 10) * 64 + l;
#pragma unroll
      for (int ct = 0; ct < 10; ++ct)
        acc2[ct] = __builtin_amdgcn_mfma_f32_16x16x32_bf16(a2f, wp[ct * 64], acc2[ct], 0, 0, 0);
    }

    // epilogue 2: s = relu(h2 + b2) @ W3 + b3, reduce over 16 col-lanes
    float part[4] = {0.f, 0.f, 0.f, 0.f};
#pragma unroll
    for (int ct = 0; ct < 10; ++ct) {
      int h = ct * 16 + m;
      float bb = (h < 150) ? b2[h] : 0.f;
      float w3 = (h < 150) ? W3[h] : 0.f;
#pragma unroll
      for (int r = 0; r < 4; ++r)
        part[r] += fmaxf(acc2[ct][r] + bb, 0.f) * w3;
    }
#pragma unroll
    for (int off = 8; off >= 1; off >>= 1) {
#pragma unroll
      for (int r = 0; r < 4; ++r) part[r] += __shfl_xor(part[r], off, 16);
    }
#pragma unroll
    for (int r = 0; r < 4; ++r) {
      if (m == r) {
        int row = w * 32 + rg * 16 + kg * 4 + r;
        out[(size_t)bi_s[row] * NSEQ + js_s[row]] = part[r] + b3v;
      }
    }
  }
}

// ---------------------------------------------------------------------------
// softmax: 4 (b,i)-rows per block, one wave each. j<i: score, j==i: 0,
// j>i: PAD after softmax.
// ---------------------------------------------------------------------------
__global__ __launch_bounds__(256) void softmax_rows(float* __restrict__ out) {
  int w = threadIdx.x >> 6, l = threadIdx.x & 63;
  int blk = blockIdx.x * 4 + w;   // 0..1535 = b*192+i
  int i = blk % NSEQ;
  size_t base = (size_t)blk * NSEQ;
  float v[3];
  float mx = NEGINF;
#pragma unroll
  for (int t = 0; t < 3; ++t) {
    int j = l + 64 * t;
    float x = (j < i) ? out[base + j] : (j == i ? 0.f : NEGINF);
    v[t] = x;
    mx = fmaxf(mx, x);
  }
#pragma unroll
  for (int off = 32; off >= 1; off >>= 1) mx = fmaxf(mx, __shfl_xor(mx, off, 64));
  float s = 0.f;
#pragma unroll
  for (int t = 0; t < 3; ++t) s += __expf(v[t] - mx);
#pragma unroll
  for (int off = 32; off >= 1; off >>= 1) s += __shfl_xor(s, off, 64);
  float inv = 1.0f / s;
#pragma unroll
  for (int t = 0; t < 3; ++t) {
    int j = l + 64 * t;
    out[base + j] = (j <= i) ? __expf(v[t] - mx) * inv : PADV;
  }
}

// ---------------------------------------------------------------------------
extern "C" void kernel_launch(void* const* d_in, const int* in_sizes, int n_in,
                              void* d_out, int out_size, void* d_ws, size_t ws_size,
                              hipStream_t stream) {
  const float* E  = (const float*)d_in[0];
  const float* W1 = (const float*)d_in[1];
  const float* b1 = (const float*)d_in[2];
  const float* W2 = (const float*)d_in[3];
  const float* b2 = (const float*)d_in[4];
  const float* W3 = (const float*)d_in[5];
  const float* b3 = (const float*)d_in[6];
  float* out = (float*)d_out;

  char* ws = (char*)d_ws;
  float*  A12   = (float*)(ws);                 // 1536*320*4 = 1,966,080 B
  __bf16* W1abp = (__bf16*)(ws + 1966080);      //   491,520 B
  __bf16* W1cp  = (__bf16*)(ws + 2457600);      //   245,760 B
  __bf16* W2p   = (__bf16*)(ws + 2703360);      //    51,200 B  (end 2,754,560)

  hipMemsetAsync(A12, 0, 1966080, stream);
  prep_pack<<<1540, 256, 0, stream>>>(W1, W2, W1abp, W1cp, W2p);
  prep_gemm<<<768, 256, 0, stream>>>(E, W1abp, A12);
  pair_mlp<<<1146, 256, 0, stream>>>(E, A12, W1cp, W2p, b1, b2, W3, b3, out);
  softmax_rows<<<384, 256, 0, stream>>>(out);
}

// Round 3
// 156.826 us; speedup vs baseline: 2.5033x; 1.4831x over previous
//
#include <hip/hip_runtime.h>
#include <hip/hip_bf16.h>

#define NSEQ   192
#define PADV   -1000.0f
#define NEGINF -1.0e30f

typedef __bf16 bf16x8 __attribute__((ext_vector_type(8)));
typedef float  f32x4  __attribute__((ext_vector_type(4)));

__device__ __forceinline__ void glds16(const void* g, void* l) {
  __builtin_amdgcn_global_load_lds(
      (const __attribute__((address_space(1))) unsigned int*)g,
      (__attribute__((address_space(3))) unsigned int*)l, 16, 0, 0);
}

// ---------------------------------------------------------------------------
// prep_pack: repack weights into bf16 MFMA B-fragment order.
//   frag (kk,ct): lane l elem e holds B[kk*32+(l>>4)*8+e][ct*16+(l&15)]
// ---------------------------------------------------------------------------
__global__ __launch_bounds__(256) void prep_pack(const float* __restrict__ W1,
                                                 const float* __restrict__ W2,
                                                 __bf16* __restrict__ W1abp,
                                                 __bf16* __restrict__ W1cp,
                                                 __bf16* __restrict__ W2p) {
  int idx = blockIdx.x * 256 + threadIdx.x;   // grid: 1540*256 == 394240 exact
  if (idx < 245760) {
    int e = idx & 7, l = (idx >> 3) & 63, t = idx >> 9;
    int ct = t % 20, kk = t / 20;             // kk 0..23
    int k = kk * 32 + ((l >> 4) << 3) + e;    // 0..767
    int hp = ct * 16 + (l & 15);              // 0..319
    int col = (hp < 160) ? hp : hp - 160;
    int rbase = (hp < 160) ? 0 : 768;
    float v = (col < 150) ? W1[(size_t)(rbase + k) * 150 + col] : 0.f;
    W1abp[idx] = (__bf16)v;
  } else if (idx < 245760 + 122880) {
    int j = idx - 245760;
    int e = j & 7, l = (j >> 3) & 63, t = j >> 9;
    int ct = t % 10, kk = t / 10;             // kk 0..23
    int k = kk * 32 + ((l >> 4) << 3) + e;
    int h = ct * 16 + (l & 15);
    float v = (h < 150) ? W1[(size_t)(1536 + k) * 150 + h] : 0.f;
    W1cp[j] = (__bf16)v;
  } else {
    int j = idx - 368640;                     // < 25600
    int e = j & 7, l = (j >> 3) & 63, t = j >> 9;
    int ct = t % 10, kk = t / 10;             // kk 0..4
    int k = kk * 32 + ((l >> 4) << 3) + e;    // 0..159
    int h = ct * 16 + (l & 15);
    float v = (k < 150 && h < 150) ? W2[(size_t)k * 150 + h] : 0.f;
    W2p[j] = (__bf16)v;
  }
}

// ---------------------------------------------------------------------------
// prep_gemm: A12[1536][320] += E @ [W1a|W1b], K split 8 ways (f32 atomics).
// ---------------------------------------------------------------------------
__global__ __launch_bounds__(256) void prep_gemm(const float* __restrict__ E,
                                                 const __bf16* __restrict__ W1abp,
                                                 float* __restrict__ A12) {
  int tid = threadIdx.x;
  int w = tid >> 6, l = tid & 63, m = l & 15, kg = l >> 4;
  int mt = blockIdx.x >> 3;                   // 0..95
  int c  = blockIdx.x & 7;                    // K-chunk 0..7
  const float* ep = E + (size_t)(mt * 16 + m) * 768 + c * 96;

  f32x4 acc[5];
#pragma unroll
  for (int u = 0; u < 5; ++u) acc[u] = (f32x4){0.f, 0.f, 0.f, 0.f};

#pragma unroll
  for (int kk = 0; kk < 3; ++kk) {
    int k = kk * 32 + kg * 8;
    f32x4 x0 = *(const f32x4*)(ep + k);
    f32x4 x1 = *(const f32x4*)(ep + k + 4);
    bf16x8 af;
#pragma unroll
    for (int e = 0; e < 4; ++e) { af[e] = (__bf16)x0[e]; af[e + 4] = (__bf16)x1[e]; }
    const bf16x8* wp = (const bf16x8*)W1abp + (size_t)(((c * 3 + kk) * 20) + w * 5) * 64 + l;
#pragma unroll
    for (int u = 0; u < 5; ++u)
      acc[u] = __builtin_amdgcn_mfma_f32_16x16x32_bf16(af, wp[u * 64], acc[u], 0, 0, 0);
  }
#pragma unroll
  for (int u = 0; u < 5; ++u)
#pragma unroll
    for (int r = 0; r < 4; ++r)
      atomicAdd(&A12[(size_t)(mt * 16 + kg * 4 + r) * 320 + (w * 5 + u) * 16 + m], acc[u][r]);
}

// ---------------------------------------------------------------------------
// pair_mlp: block = 16i x 8j tile of pairs. 4 waves; wave w owns j-cols
// {w*2, w*2+1} (rg=0/1), 16 i-rows each => 32 pairs/wave.
//   W1c k-slice : LDS (global_load_lds, dbuf, shared by 4 waves)
//   e_i slice   : LDS f32 [16][32], XOR-swizzled chunks, write-late staging
//   e_j slice   : registers (wave-uniform row per rg), prefetched
//   GEMM2 W2    : LDS (glds, dbuf, shared), h1 both rgs in LDS
// ---------------------------------------------------------------------------
__global__ __launch_bounds__(256) void pair_mlp(
    const float* __restrict__ E, const float* __restrict__ A12,
    const __bf16* __restrict__ W1cp, const __bf16* __restrict__ W2p,
    const float* __restrict__ b1, const float* __restrict__ b2,
    const float* __restrict__ W3, const float* __restrict__ b3,
    float* __restrict__ out) {
  __shared__ alignas(16) __bf16 Wbuf[2][5120];        // 20480 B
  __shared__ alignas(16) float  Eib[2][512];          //  4096 B
  __shared__ alignas(16) __bf16 h1s[4][2][16][168];   // 43008 B

  int tid = threadIdx.x;
  int w = tid >> 6, l = tid & 63;
  int m = l & 15, kg = l >> 4;

  // tile decode: blk -> (b, it, jt); per-batch tiles = sum(2it+2) = 156
  int blk = blockIdx.x;
  int b = blk / 156, r0 = blk - b * 156;
  int it = (int)((sqrtf(4.f * (float)r0 + 1.f) - 1.f) * 0.5f);
  while (it * it + it > r0) --it;
  while ((it + 1) * (it + 1) + it + 1 <= r0) ++it;
  int jt = r0 - it * it - it;                 // 0..2it+1

  const int ibase = b * NSEQ + it * 16;       // global i-row base
  const int jrow0 = b * NSEQ + jt * 8 + w * 2;// + rg

  // ---- acc init: A1[i] + A2[j] + b1 at (row kg*4+rr, col ct*16+m) ----
  f32x4 acc[2][10];
#pragma unroll
  for (int rg = 0; rg < 2; ++rg) {
    const float* a2p = A12 + (size_t)(jrow0 + rg) * 320 + 160;
#pragma unroll
    for (int ct = 0; ct < 10; ++ct) {
      int h = ct * 16 + m;
      float base2 = a2p[h] + ((h < 150) ? b1[h] : 0.f);
#pragma unroll
      for (int rr = 0; rr < 4; ++rr) {
        const float* a1p = A12 + (size_t)(ibase + kg * 4 + rr) * 320;
        acc[rg][ct][rr] = a1p[h] + base2;
      }
    }
  }

  // ---- staging helpers (inline) ----
  int erow = tid >> 3, ec = tid & 7;          // tid<128: Ei chunk owner
  const float* eisrc = E + (size_t)(ibase + erow) * 768 + ec * 4;
  int eoff = erow * 32 + ((ec ^ (erow & 7)) << 2);   // XOR-swizzled f32 offset

  // prologue: stage kk=0
#pragma unroll
  for (int f = w; f < 10; f += 4)
    glds16(W1cp + (size_t)(0 * 10 + f) * 512 + l * 8, &Wbuf[0][f * 512]);
  f32x4 yc[2][2], yn[2][2];
#pragma unroll
  for (int rg = 0; rg < 2; ++rg)
#pragma unroll
    for (int t = 0; t < 2; ++t)
      yc[rg][t] = *(const f32x4*)(E + (size_t)(jrow0 + rg) * 768 + kg * 8 + t * 4);
  if (tid < 128) {
    f32x4 e0 = *(const f32x4*)(eisrc);
    *(f32x4*)&Eib[0][eoff] = e0;
  }
  __syncthreads();

  for (int kk = 0; kk < 24; ++kk) {
    int bs = kk & 1;
    bool more = (kk + 1) < 24;
    f32x4 est;
    if (more) {
#pragma unroll
      for (int f = w; f < 10; f += 4)
        glds16(W1cp + (size_t)((kk + 1) * 10 + f) * 512 + l * 8, &Wbuf[bs ^ 1][f * 512]);
      if (tid < 128) est = *(const f32x4*)(eisrc + (kk + 1) * 32);
#pragma unroll
      for (int rg = 0; rg < 2; ++rg)
#pragma unroll
        for (int t = 0; t < 2; ++t)
          yn[rg][t] = *(const f32x4*)(E + (size_t)(jrow0 + rg) * 768 + (kk + 1) * 32 + kg * 8 + t * 4);
    }

    // compute kk
    f32x4 xi0 = *(const f32x4*)&Eib[bs][m * 32 + (((2 * kg + 0) ^ (m & 7)) << 2)];
    f32x4 xi1 = *(const f32x4*)&Eib[bs][m * 32 + (((2 * kg + 1) ^ (m & 7)) << 2)];
    bf16x8 af0, af1;
#pragma unroll
    for (int e = 0; e < 4; ++e) {
      af0[e]     = (__bf16)(xi0[e] * yc[0][0][e]);
      af0[e + 4] = (__bf16)(xi1[e] * yc[0][1][e]);
      af1[e]     = (__bf16)(xi0[e] * yc[1][0][e]);
      af1[e + 4] = (__bf16)(xi1[e] * yc[1][1][e]);
    }
#pragma unroll
    for (int ct = 0; ct < 10; ++ct) {
      bf16x8 wf = *(const bf16x8*)&Wbuf[bs][ct * 512 + l * 8];
      acc[0][ct] = __builtin_amdgcn_mfma_f32_16x16x32_bf16(af0, wf, acc[0][ct], 0, 0, 0);
      acc[1][ct] = __builtin_amdgcn_mfma_f32_16x16x32_bf16(af1, wf, acc[1][ct], 0, 0, 0);
    }

    if (more && tid < 128) *(f32x4*)&Eib[bs ^ 1][eoff] = est;   // write-late
    __syncthreads();
    if (more) {
#pragma unroll
      for (int rg = 0; rg < 2; ++rg)
#pragma unroll
        for (int t = 0; t < 2; ++t) yc[rg][t] = yn[rg][t];
    }
  }

  // ---- h1 -> LDS (wave-private, both row-groups) ----
#pragma unroll
  for (int rg = 0; rg < 2; ++rg)
#pragma unroll
    for (int rr = 0; rr < 4; ++rr)
#pragma unroll
      for (int ct = 0; ct < 10; ++ct)
        h1s[w][rg][kg * 4 + rr][ct * 16 + m] = (__bf16)fmaxf(acc[rg][ct][rr], 0.f);

  // ---- GEMM2: h2 = h1 @ W2 (K=160, 5 steps, W2 slices in LDS dbuf) ----
#pragma unroll
  for (int f = w; f < 10; f += 4)
    glds16(W2p + (size_t)(0 * 10 + f) * 512 + l * 8, &Wbuf[0][f * 512]);
  __syncthreads();

  f32x4 acc2[2][10];
#pragma unroll
  for (int rg = 0; rg < 2; ++rg)
#pragma unroll
    for (int u = 0; u < 10; ++u) acc2[rg][u] = (f32x4){0.f, 0.f, 0.f, 0.f};

  for (int kk2 = 0; kk2 < 5; ++kk2) {
    int bs = kk2 & 1;
    if (kk2 < 4) {
#pragma unroll
      for (int f = w; f < 10; f += 4)
        glds16(W2p + (size_t)((kk2 + 1) * 10 + f) * 512 + l * 8, &Wbuf[bs ^ 1][f * 512]);
    }
    bf16x8 a20 = *(const bf16x8*)&h1s[w][0][m][kk2 * 32 + kg * 8];
    bf16x8 a21 = *(const bf16x8*)&h1s[w][1][m][kk2 * 32 + kg * 8];
#pragma unroll
    for (int ct = 0; ct < 10; ++ct) {
      bf16x8 wf = *(const bf16x8*)&Wbuf[bs][ct * 512 + l * 8];
      acc2[0][ct] = __builtin_amdgcn_mfma_f32_16x16x32_bf16(a20, wf, acc2[0][ct], 0, 0, 0);
      acc2[1][ct] = __builtin_amdgcn_mfma_f32_16x16x32_bf16(a21, wf, acc2[1][ct], 0, 0, 0);
    }
    __syncthreads();
  }

  // ---- epilogue 2: s = relu(h2+b2) @ W3 + b3; store valid pairs ----
  float b3v = b3[0];
#pragma unroll
  for (int rg = 0; rg < 2; ++rg) {
    float part[4] = {0.f, 0.f, 0.f, 0.f};
#pragma unroll
    for (int ct = 0; ct < 10; ++ct) {
      int h = ct * 16 + m;
      float bb = (h < 150) ? b2[h] : 0.f;
      float w3 = (h < 150) ? W3[h] : 0.f;
#pragma unroll
      for (int rr = 0; rr < 4; ++rr)
        part[rr] += fmaxf(acc2[rg][ct][rr] + bb, 0.f) * w3;
    }
#pragma unroll
    for (int off = 8; off >= 1; off >>= 1) {
#pragma unroll
      for (int rr = 0; rr < 4; ++rr) part[rr] += __shfl_xor(part[rr], off, 16);
    }
#pragma unroll
    for (int rr = 0; rr < 4; ++rr) {
      if (m == rr) {
        int il = it * 16 + kg * 4 + rr;
        int jl = jt * 8 + w * 2 + rg;
        if (jl < il)
          out[((size_t)(b * NSEQ + il)) * NSEQ + jl] = part[rr] + b3v;
      }
    }
  }
}

// ---------------------------------------------------------------------------
// softmax: 4 (b,i)-rows per block, one wave each.
// ---------------------------------------------------------------------------
__global__ __launch_bounds__(256) void softmax_rows(float* __restrict__ out) {
  int w = threadIdx.x >> 6, l = threadIdx.x & 63;
  int blk = blockIdx.x * 4 + w;   // 0..1535 = b*192+i
  int i = blk % NSEQ;
  size_t base = (size_t)blk * NSEQ;
  float v[3];
  float mx = NEGINF;
#pragma unroll
  for (int t = 0; t < 3; ++t) {
    int j = l + 64 * t;
    float x = (j < i) ? out[base + j] : (j == i ? 0.f : NEGINF);
    v[t] = x;
    mx = fmaxf(mx, x);
  }
#pragma unroll
  for (int off = 32; off >= 1; off >>= 1) mx = fmaxf(mx, __shfl_xor(mx, off, 64));
  float s = 0.f;
#pragma unroll
  for (int t = 0; t < 3; ++t) s += __expf(v[t] - mx);
#pragma unroll
  for (int off = 32; off >= 1; off >>= 1) s += __shfl_xor(s, off, 64);
  float inv = 1.0f / s;
#pragma unroll
  for (int t = 0; t < 3; ++t) {
    int j = l + 64 * t;
    out[base + j] = (j <= i) ? __expf(v[t] - mx) * inv : PADV;
  }
}

// ---------------------------------------------------------------------------
extern "C" void kernel_launch(void* const* d_in, const int* in_sizes, int n_in,
                              void* d_out, int out_size, void* d_ws, size_t ws_size,
                              hipStream_t stream) {
  const float* E  = (const float*)d_in[0];
  const float* W1 = (const float*)d_in[1];
  const float* b1 = (const float*)d_in[2];
  const float* W2 = (const float*)d_in[3];
  const float* b2 = (const float*)d_in[4];
  const float* W3 = (const float*)d_in[5];
  const float* b3 = (const float*)d_in[6];
  float* out = (float*)d_out;

  char* ws = (char*)d_ws;
  float*  A12   = (float*)(ws);                 // 1536*320*4 = 1,966,080 B
  __bf16* W1abp = (__bf16*)(ws + 1966080);      //   491,520 B
  __bf16* W1cp  = (__bf16*)(ws + 2457600);      //   245,760 B
  __bf16* W2p   = (__bf16*)(ws + 2703360);      //    51,200 B

  hipMemsetAsync(A12, 0, 1966080, stream);
  prep_pack<<<1540, 256, 0, stream>>>(W1, W2, W1abp, W1cp, W2p);
  prep_gemm<<<768, 256, 0, stream>>>(E, W1abp, A12);
  pair_mlp<<<1248, 256, 0, stream>>>(E, A12, W1cp, W2p, b1, b2, W3, b3, out);
  softmax_rows<<<384, 256, 0, stream>>>(out);
}

// Round 4
// 109.661 us; speedup vs baseline: 3.5799x; 1.4301x over previous
//
#include <hip/hip_runtime.h>
#include <hip/hip_bf16.h>

#define NSEQ   192
#define PADV   -1000.0f
#define NEGINF -1.0e30f

typedef __bf16 bf16x8 __attribute__((ext_vector_type(8)));
typedef float  f32x4  __attribute__((ext_vector_type(4)));

__device__ __forceinline__ void glds16(const void* g, void* l) {
  __builtin_amdgcn_global_load_lds(
      (const __attribute__((address_space(1))) unsigned int*)g,
      (__attribute__((address_space(3))) unsigned int*)l, 16, 0, 0);
}

#define MFMA16(a, b, c) __builtin_amdgcn_mfma_f32_16x16x32_bf16((a), (b), (c), 0, 0, 0)

// ---------------------------------------------------------------------------
// prep_pack: repack weights into bf16 MFMA B-fragment order.
//   frag (kk,ct): lane l elem e holds B[kk*32+(l>>4)*8+e][ct*16+(l&15)]
// ---------------------------------------------------------------------------
__global__ __launch_bounds__(256) void prep_pack(const float* __restrict__ W1,
                                                 const float* __restrict__ W2,
                                                 __bf16* __restrict__ W1abp,
                                                 __bf16* __restrict__ W1cp,
                                                 __bf16* __restrict__ W2p) {
  int idx = blockIdx.x * 256 + threadIdx.x;   // grid: 1540*256 == 394240 exact
  if (idx < 245760) {
    int e = idx & 7, l = (idx >> 3) & 63, t = idx >> 9;
    int ct = t % 20, kk = t / 20;             // kk 0..23
    int k = kk * 32 + ((l >> 4) << 3) + e;    // 0..767
    int hp = ct * 16 + (l & 15);              // 0..319
    int col = (hp < 160) ? hp : hp - 160;
    int rbase = (hp < 160) ? 0 : 768;
    float v = (col < 150) ? W1[(size_t)(rbase + k) * 150 + col] : 0.f;
    W1abp[idx] = (__bf16)v;
  } else if (idx < 245760 + 122880) {
    int j = idx - 245760;
    int e = j & 7, l = (j >> 3) & 63, t = j >> 9;
    int ct = t % 10, kk = t / 10;             // kk 0..23
    int k = kk * 32 + ((l >> 4) << 3) + e;
    int h = ct * 16 + (l & 15);
    float v = (h < 150) ? W1[(size_t)(1536 + k) * 150 + h] : 0.f;
    W1cp[j] = (__bf16)v;
  } else {
    int j = idx - 368640;                     // < 25600
    int e = j & 7, l = (j >> 3) & 63, t = j >> 9;
    int ct = t % 10, kk = t / 10;             // kk 0..4
    int k = kk * 32 + ((l >> 4) << 3) + e;    // 0..159
    int h = ct * 16 + (l & 15);
    float v = (k < 150 && h < 150) ? W2[(size_t)k * 150 + h] : 0.f;
    W2p[j] = (__bf16)v;
  }
}

// ---------------------------------------------------------------------------
// prep_gemm: A12[1536][320] += E @ [W1a|W1b], K split 8 ways (f32 atomics).
// ---------------------------------------------------------------------------
__global__ __launch_bounds__(256) void prep_gemm(const float* __restrict__ E,
                                                 const __bf16* __restrict__ W1abp,
                                                 float* __restrict__ A12) {
  int tid = threadIdx.x;
  int w = tid >> 6, l = tid & 63, m = l & 15, kg = l >> 4;
  int mt = blockIdx.x >> 3;                   // 0..95
  int c  = blockIdx.x & 7;                    // K-chunk 0..7
  const float* ep = E + (size_t)(mt * 16 + m) * 768 + c * 96;

  f32x4 acc[5];
#pragma unroll
  for (int u = 0; u < 5; ++u) acc[u] = (f32x4){0.f, 0.f, 0.f, 0.f};

#pragma unroll
  for (int kk = 0; kk < 3; ++kk) {
    int k = kk * 32 + kg * 8;
    f32x4 x0 = *(const f32x4*)(ep + k);
    f32x4 x1 = *(const f32x4*)(ep + k + 4);
    bf16x8 af;
#pragma unroll
    for (int e = 0; e < 4; ++e) { af[e] = (__bf16)x0[e]; af[e + 4] = (__bf16)x1[e]; }
    const bf16x8* wp = (const bf16x8*)W1abp + (size_t)(((c * 3 + kk) * 20) + w * 5) * 64 + l;
#pragma unroll
    for (int u = 0; u < 5; ++u)
      acc[u] = MFMA16(af, wp[u * 64], acc[u]);
  }
#pragma unroll
  for (int u = 0; u < 5; ++u)
#pragma unroll
    for (int r = 0; r < 4; ++r)
      atomicAdd(&A12[(size_t)(mt * 16 + kg * 4 + r) * 320 + (w * 5 + u) * 16 + m], acc[u][r]);
}

// ---------------------------------------------------------------------------
// pair_mlp: block = 16i x 8j tile. 4 waves; wave w owns j-cols {w*2, w*2+1}.
// GEMM1: BK=64 pipeline, W1c slices in LDS (glds, dbuf, raw barriers,
// counted vmcnt); e_i per-lane regs, e_j wave-uniform regs, depth-1 prefetch.
// GEMM2: all of W2 staged once in LDS; h1 one row-group at a time
// (wave-private LDS), zero barriers in the GEMM2 loop.
// ---------------------------------------------------------------------------
__global__ __launch_bounds__(256, 2) void pair_mlp(
    const float* __restrict__ E, const float* __restrict__ A12,
    const __bf16* __restrict__ W1cp, const __bf16* __restrict__ W2p,
    const float* __restrict__ b1, const float* __restrict__ b2,
    const float* __restrict__ W3, const float* __restrict__ b3,
    float* __restrict__ out) {
  __shared__ alignas(16) char pool[72704];
  __bf16* Wb  = (__bf16*)pool;              // GEMM1: [2][20][512] frags; GEMM2: [50][512]
  __bf16* h1s = (__bf16*)(pool + 51200);    // [4 waves][16 rows][168]

  const int tid = threadIdx.x;
  const int w = tid >> 6, l = tid & 63;
  const int m = l & 15, kg = l >> 4;

  // tile decode: blk -> (b, it, jt); per-batch tiles = sum(2it+2) = 156
  int blk = blockIdx.x;
  int b = blk / 156, r0 = blk - b * 156;
  int it = (int)((sqrtf(4.f * (float)r0 + 1.f) - 1.f) * 0.5f);
  while (it * it + it > r0) --it;
  while ((it + 1) * (it + 1) + (it + 1) <= r0) ++it;
  int jt = r0 - it * it - it;               // 0..2it+1

  const int ibase = b * NSEQ + it * 16;
  const int jrow0 = b * NSEQ + jt * 8 + w * 2;

  // ---- acc init: A1[i] + A2[j] + b1 at (row kg*4+rr, col ct*16+m) ----
  f32x4 acc[2][10];
#pragma unroll
  for (int rg = 0; rg < 2; ++rg) {
    const float* a2p = A12 + (size_t)(jrow0 + rg) * 320 + 160;
#pragma unroll
    for (int ct = 0; ct < 10; ++ct) {
      int h = ct * 16 + m;
      float base2 = a2p[h] + ((h < 150) ? b1[h] : 0.f);
#pragma unroll
      for (int rr = 0; rr < 4; ++rr)
        acc[rg][ct][rr] = A12[(size_t)(ibase + kg * 4 + rr) * 320 + h] + base2;
    }
  }

  const float* eibase = E + (size_t)(ibase + m) * 768;
  const float* ejb0   = E + (size_t)jrow0 * 768;
  const float* ejb1   = E + (size_t)(jrow0 + 1) * 768;

  // ---- prologue: stage tile 0 (W into Wb half 0), load e regs tile 0 ----
#pragma unroll
  for (int q = 0; q < 5; ++q)
    glds16(W1cp + (size_t)(w * 5 + q) * 512 + l * 8, Wb + (w * 5 + q) * 512);
  f32x4 eic[4], ejc[2][4], ein[4], ejn[2][4];
#pragma unroll
  for (int q = 0; q < 4; ++q) {
    int off = (q >> 1) * 32 + kg * 8 + (q & 1) * 4;
    eic[q]    = *(const f32x4*)(eibase + off);
    ejc[0][q] = *(const f32x4*)(ejb0 + off);
    ejc[1][q] = *(const f32x4*)(ejb1 + off);
  }

  // ---- GEMM1 main loop: 12 iters of BK=64; uniform 17 VM ops per iter ----
  for (int t = 0; t < 12; ++t) {
    int tn = (t < 11) ? t + 1 : 11;         // clamp keeps counts uniform
    int bn = (t + 1) & 1;
#pragma unroll
    for (int q = 0; q < 5; ++q)
      glds16(W1cp + ((size_t)tn * 20 + w * 5 + q) * 512 + l * 8,
             Wb + (bn * 20 + w * 5 + q) * 512);
#pragma unroll
    for (int q = 0; q < 4; ++q) {
      int off = tn * 64 + (q >> 1) * 32 + kg * 8 + (q & 1) * 4;
      ein[q]    = *(const f32x4*)(eibase + off);
      ejn[0][q] = *(const f32x4*)(ejb0 + off);
      ejn[1][q] = *(const f32x4*)(ejb1 + off);
    }
    asm volatile("s_waitcnt vmcnt(17)" ::: "memory");
    __builtin_amdgcn_s_barrier();

    const __bf16* wb = Wb + (t & 1) * 10240;
#pragma unroll
    for (int s = 0; s < 2; ++s) {
      bf16x8 af0, af1;
#pragma unroll
      for (int e = 0; e < 4; ++e) {
        af0[e]     = (__bf16)(eic[2 * s][e]     * ejc[0][2 * s][e]);
        af0[e + 4] = (__bf16)(eic[2 * s + 1][e] * ejc[0][2 * s + 1][e]);
        af1[e]     = (__bf16)(eic[2 * s][e]     * ejc[1][2 * s][e]);
        af1[e + 4] = (__bf16)(eic[2 * s + 1][e] * ejc[1][2 * s + 1][e]);
      }
#pragma unroll
      for (int ct = 0; ct < 10; ++ct) {
        bf16x8 wf = *(const bf16x8*)(wb + (s * 10 + ct) * 512 + l * 8);
        acc[0][ct] = MFMA16(af0, wf, acc[0][ct]);
        acc[1][ct] = MFMA16(af1, wf, acc[1][ct]);
      }
    }
    __builtin_amdgcn_s_barrier();
#pragma unroll
    for (int q = 0; q < 4; ++q) {
      eic[q] = ein[q]; ejc[0][q] = ejn[0][q]; ejc[1][q] = ejn[1][q];
    }
  }

  // ---- h1(rg0) -> wave-private LDS ----
#pragma unroll
  for (int rr = 0; rr < 4; ++rr)
#pragma unroll
    for (int ct = 0; ct < 10; ++ct)
      h1s[(w * 16 + kg * 4 + rr) * 168 + ct * 16 + m] =
          (__bf16)fmaxf(acc[0][ct][rr], 0.f);

  // ---- stage ALL of W2 (50 frags) into Wb; single drain ----
  for (int f = w; f < 50; f += 4)
    glds16(W2p + (size_t)f * 512 + l * 8, Wb + f * 512);
  __syncthreads();

  float b3v = b3[0];
#pragma unroll
  for (int rg = 0; rg < 2; ++rg) {
    if (rg == 1) {  // overwrite h1s with rg1 (same-wave DS order is safe)
#pragma unroll
      for (int rr = 0; rr < 4; ++rr)
#pragma unroll
        for (int ct = 0; ct < 10; ++ct)
          h1s[(w * 16 + kg * 4 + rr) * 168 + ct * 16 + m] =
              (__bf16)fmaxf(acc[1][ct][rr], 0.f);
    }
    f32x4 acc2[10];
#pragma unroll
    for (int u = 0; u < 10; ++u) acc2[u] = (f32x4){0.f, 0.f, 0.f, 0.f};
#pragma unroll
    for (int s = 0; s < 5; ++s) {
      bf16x8 a2f = *(const bf16x8*)&h1s[(w * 16 + m) * 168 + s * 32 + kg * 8];
#pragma unroll
      for (int ct = 0; ct < 10; ++ct) {
        bf16x8 wf = *(const bf16x8*)(Wb + (s * 10 + ct) * 512 + l * 8);
        acc2[ct] = MFMA16(a2f, wf, acc2[ct]);
      }
    }
    // epilogue: s = relu(h2 + b2) @ W3 + b3, reduce over 16 col-lanes
    float part[4] = {0.f, 0.f, 0.f, 0.f};
#pragma unroll
    for (int ct = 0; ct < 10; ++ct) {
      int h = ct * 16 + m;
      float bb = (h < 150) ? b2[h] : 0.f;
      float w3 = (h < 150) ? W3[h] : 0.f;
#pragma unroll
      for (int rr = 0; rr < 4; ++rr)
        part[rr] += fmaxf(acc2[ct][rr] + bb, 0.f) * w3;
    }
#pragma unroll
    for (int off = 8; off >= 1; off >>= 1) {
#pragma unroll
      for (int rr = 0; rr < 4; ++rr) part[rr] += __shfl_xor(part[rr], off, 16);
    }
#pragma unroll
    for (int rr = 0; rr < 4; ++rr) {
      if (m == rr) {
        int il = it * 16 + kg * 4 + rr;
        int jl = jt * 8 + w * 2 + rg;
        if (jl < il)
          out[((size_t)(b * NSEQ + il)) * NSEQ + jl] = part[rr] + b3v;
      }
    }
  }
}

// ---------------------------------------------------------------------------
// softmax: 4 (b,i)-rows per block, one wave each.
// ---------------------------------------------------------------------------
__global__ __launch_bounds__(256) void softmax_rows(float* __restrict__ out) {
  int w = threadIdx.x >> 6, l = threadIdx.x & 63;
  int blk = blockIdx.x * 4 + w;   // 0..1535 = b*192+i
  int i = blk % NSEQ;
  size_t base = (size_t)blk * NSEQ;
  float v[3];
  float mx = NEGINF;
#pragma unroll
  for (int t = 0; t < 3; ++t) {
    int j = l + 64 * t;
    float x = (j < i) ? out[base + j] : (j == i ? 0.f : NEGINF);
    v[t] = x;
    mx = fmaxf(mx, x);
  }
#pragma unroll
  for (int off = 32; off >= 1; off >>= 1) mx = fmaxf(mx, __shfl_xor(mx, off, 64));
  float s = 0.f;
#pragma unroll
  for (int t = 0; t < 3; ++t) s += __expf(v[t] - mx);
#pragma unroll
  for (int off = 32; off >= 1; off >>= 1) s += __shfl_xor(s, off, 64);
  float inv = 1.0f / s;
#pragma unroll
  for (int t = 0; t < 3; ++t) {
    int j = l + 64 * t;
    out[base + j] = (j <= i) ? __expf(v[t] - mx) * inv : PADV;
  }
}

// ---------------------------------------------------------------------------
extern "C" void kernel_launch(void* const* d_in, const int* in_sizes, int n_in,
                              void* d_out, int out_size, void* d_ws, size_t ws_size,
                              hipStream_t stream) {
  const float* E  = (const float*)d_in[0];
  const float* W1 = (const float*)d_in[1];
  const float* b1 = (const float*)d_in[2];
  const float* W2 = (const float*)d_in[3];
  const float* b2 = (const float*)d_in[4];
  const float* W3 = (const float*)d_in[5];
  const float* b3 = (const float*)d_in[6];
  float* out = (float*)d_out;

  char* ws = (char*)d_ws;
  float*  A12   = (float*)(ws);                 // 1536*320*4 = 1,966,080 B
  __bf16* W1abp = (__bf16*)(ws + 1966080);      //   491,520 B
  __bf16* W1cp  = (__bf16*)(ws + 2457600);      //   245,760 B
  __bf16* W2p   = (__bf16*)(ws + 2703360);      //    51,200 B

  hipMemsetAsync(A12, 0, 1966080, stream);
  prep_pack<<<1540, 256, 0, stream>>>(W1, W2, W1abp, W1cp, W2p);
  prep_gemm<<<768, 256, 0, stream>>>(E, W1abp, A12);
  pair_mlp<<<1248, 256, 0, stream>>>(E, A12, W1cp, W2p, b1, b2, W3, b3, out);
  softmax_rows<<<384, 256, 0, stream>>>(out);
}

// Round 5
// 88.427 us; speedup vs baseline: 4.4396x; 1.2401x over previous
//
#include <hip/hip_runtime.h>
#include <hip/hip_bf16.h>

#define NSEQ   192
#define PADV   -1000.0f
#define NEGINF -1.0e30f

typedef __bf16 bf16x8 __attribute__((ext_vector_type(8)));
typedef float  f32x4  __attribute__((ext_vector_type(4)));

__device__ __forceinline__ void glds16(const void* g, void* l) {
  __builtin_amdgcn_global_load_lds(
      (const __attribute__((address_space(1))) unsigned int*)g,
      (__attribute__((address_space(3))) unsigned int*)l, 16, 0, 0);
}

#define MFMA16(a, b, c) __builtin_amdgcn_mfma_f32_16x16x32_bf16((a), (b), (c), 0, 0, 0)

// ---------------------------------------------------------------------------
// prep_pack: repack weights into bf16 MFMA B-fragment order.
//   frag (kk,ct): lane l elem e holds B[kk*32+(l>>4)*8+e][ct*16+(l&15)]
// ---------------------------------------------------------------------------
__global__ __launch_bounds__(256) void prep_pack(const float* __restrict__ W1,
                                                 const float* __restrict__ W2,
                                                 __bf16* __restrict__ W1abp,
                                                 __bf16* __restrict__ W1cp,
                                                 __bf16* __restrict__ W2p) {
  int idx = blockIdx.x * 256 + threadIdx.x;   // grid: 1540*256 == 394240 exact
  if (idx < 245760) {
    int e = idx & 7, l = (idx >> 3) & 63, t = idx >> 9;
    int ct = t % 20, kk = t / 20;             // kk 0..23
    int k = kk * 32 + ((l >> 4) << 3) + e;    // 0..767
    int hp = ct * 16 + (l & 15);              // 0..319
    int col = (hp < 160) ? hp : hp - 160;
    int rbase = (hp < 160) ? 0 : 768;
    float v = (col < 150) ? W1[(size_t)(rbase + k) * 150 + col] : 0.f;
    W1abp[idx] = (__bf16)v;
  } else if (idx < 245760 + 122880) {
    int j = idx - 245760;
    int e = j & 7, l = (j >> 3) & 63, t = j >> 9;
    int ct = t % 10, kk = t / 10;             // kk 0..23
    int k = kk * 32 + ((l >> 4) << 3) + e;
    int h = ct * 16 + (l & 15);
    float v = (h < 150) ? W1[(size_t)(1536 + k) * 150 + h] : 0.f;
    W1cp[j] = (__bf16)v;
  } else {
    int j = idx - 368640;                     // < 25600
    int e = j & 7, l = (j >> 3) & 63, t = j >> 9;
    int ct = t % 10, kk = t / 10;             // kk 0..4
    int k = kk * 32 + ((l >> 4) << 3) + e;    // 0..159
    int h = ct * 16 + (l & 15);
    float v = (k < 150 && h < 150) ? W2[(size_t)k * 150 + h] : 0.f;
    W2p[j] = (__bf16)v;
  }
}

// ---------------------------------------------------------------------------
// prep_gemm: A12[1536][320] += E @ [W1a|W1b], K split 8 ways (f32 atomics).
// ---------------------------------------------------------------------------
__global__ __launch_bounds__(256) void prep_gemm(const float* __restrict__ E,
                                                 const __bf16* __restrict__ W1abp,
                                                 float* __restrict__ A12) {
  int tid = threadIdx.x;
  int w = tid >> 6, l = tid & 63, m = l & 15, kg = l >> 4;
  int mt = blockIdx.x >> 3;                   // 0..95
  int c  = blockIdx.x & 7;                    // K-chunk 0..7
  const float* ep = E + (size_t)(mt * 16 + m) * 768 + c * 96;

  f32x4 acc[5];
#pragma unroll
  for (int u = 0; u < 5; ++u) acc[u] = (f32x4){0.f, 0.f, 0.f, 0.f};

#pragma unroll
  for (int kk = 0; kk < 3; ++kk) {
    int k = kk * 32 + kg * 8;
    f32x4 x0 = *(const f32x4*)(ep + k);
    f32x4 x1 = *(const f32x4*)(ep + k + 4);
    bf16x8 af;
#pragma unroll
    for (int e = 0; e < 4; ++e) { af[e] = (__bf16)x0[e]; af[e + 4] = (__bf16)x1[e]; }
    const bf16x8* wp = (const bf16x8*)W1abp + (size_t)(((c * 3 + kk) * 20) + w * 5) * 64 + l;
#pragma unroll
    for (int u = 0; u < 5; ++u)
      acc[u] = MFMA16(af, wp[u * 64], acc[u]);
  }
#pragma unroll
  for (int u = 0; u < 5; ++u)
#pragma unroll
    for (int r = 0; r < 4; ++r)
      atomicAdd(&A12[(size_t)(mt * 16 + kg * 4 + r) * 320 + (w * 5 + u) * 16 + m], acc[u][r]);
}

// ---------------------------------------------------------------------------
// pair_mlp: block = 16i x 8j tile. 4 waves; wave w owns j-cols {w*2, w*2+1}.
// Prologue stages e_i (16 rows, XOR-swizzled bf16) + e_j (8 rows, linear
// bf16) into LDS once. GEMM1 loop: only VMEM = 5 uniform glds16/wave/iter
// (W1c k-tile dbuf), counted vmcnt(5) + raw barriers => compiler-proof
// pipeline. GEMM2: W2 slice-dbuf in Wb half0; h1(rg1) in Wb half1; h1(rg0)
// unioned over eib.
// ---------------------------------------------------------------------------
__global__ __launch_bounds__(256, 2) void pair_mlp(
    const float* __restrict__ E, const float* __restrict__ A12,
    const __bf16* __restrict__ W1cp, const __bf16* __restrict__ W2p,
    const float* __restrict__ b1, const float* __restrict__ b2,
    const float* __restrict__ W3, const float* __restrict__ b3,
    float* __restrict__ out) {
  __shared__ alignas(16) char pool[77824];
  // GEMM1: Wb [0,40960) 2 halves x 20 frags x 1024B; eib [40960,65536)
  //        16 rows x 1536B swizzled; ejb [65536,77824) 8 rows x 1536B.
  // GEMM2: W2 dbuf [0,20480); h1 rg1 [20480,40960) stride 160;
  //        h1 rg0 [40960,62464) stride 168.
  __bf16* Wb   = (__bf16*)pool;
  char*   eib  = pool + 40960;
  char*   ejb  = pool + 65536;
  __bf16* W2b  = (__bf16*)pool;
  __bf16* h1r1 = (__bf16*)(pool + 20480);
  __bf16* h1r0 = (__bf16*)(pool + 40960);

  const int tid = threadIdx.x;
  const int w = tid >> 6, l = tid & 63;
  const int m = l & 15, kg = l >> 4;

  // tile decode: blk -> (b, it, jt); per-batch tiles = sum(2it+2) = 156
  int blk = blockIdx.x;
  int b = blk / 156, r0 = blk - b * 156;
  int it = (int)((sqrtf(4.f * (float)r0 + 1.f) - 1.f) * 0.5f);
  while (it * it + it > r0) --it;
  while ((it + 1) * (it + 1) + (it + 1) <= r0) ++it;
  int jt = r0 - it * it - it;               // 0..2it+1

  const int ibase = b * NSEQ + it * 16;
  const int jbase = b * NSEQ + jt * 8;

  // ---- issue W tile-0 stage first (oldest in vmcnt queue) ----
#pragma unroll
  for (int q = 0; q < 5; ++q)
    glds16(W1cp + (size_t)(w * 5 + q) * 512 + l * 8, Wb + (w * 5 + q) * 512);

  // ---- stage e_i (swizzled) and e_j (linear) as bf16 into LDS ----
  {
    int r = tid >> 4, c0 = tid & 15;        // e_i: 16 rows x 96 chunks(16B)
    const float* src = E + (size_t)(ibase + r) * 768;
#pragma unroll
    for (int p = 0; p < 6; ++p) {
      int c = c0 + 16 * p;
      int kf = ((c * 16) ^ ((r & 7) << 4)) >> 2;   // source f32 index
      f32x4 a = *(const f32x4*)(src + kf);
      f32x4 bq = *(const f32x4*)(src + kf + 4);
      bf16x8 v;
#pragma unroll
      for (int e = 0; e < 4; ++e) { v[e] = (__bf16)a[e]; v[e + 4] = (__bf16)bq[e]; }
      *(bf16x8*)(eib + r * 1536 + c * 16) = v;
    }
    int r2 = tid >> 5, c02 = tid & 31;      // e_j: 8 rows x 96 chunks
    const float* src2 = E + (size_t)(jbase + r2) * 768;
#pragma unroll
    for (int p = 0; p < 3; ++p) {
      int c = c02 + 32 * p;
      const float* sp = src2 + c * 8;
      f32x4 a = *(const f32x4*)(sp);
      f32x4 bq = *(const f32x4*)(sp + 4);
      bf16x8 v;
#pragma unroll
      for (int e = 0; e < 4; ++e) { v[e] = (__bf16)a[e]; v[e + 4] = (__bf16)bq[e]; }
      *(bf16x8*)(ejb + r2 * 1536 + c * 16) = v;
    }
  }

  // ---- acc init: A1[i] + A2[j] + b1 at (row kg*4+rr, col ct*16+m) ----
  f32x4 acc[2][10];
#pragma unroll
  for (int rg = 0; rg < 2; ++rg) {
    const float* a2p = A12 + (size_t)(jbase + w * 2 + rg) * 320 + 160;
#pragma unroll
    for (int ct = 0; ct < 10; ++ct) {
      int h = ct * 16 + m;
      float base2 = a2p[h] + ((h < 150) ? b1[h] : 0.f);
#pragma unroll
      for (int rr = 0; rr < 4; ++rr)
        acc[rg][ct][rr] = A12[(size_t)(ibase + kg * 4 + rr) * 320 + h] + base2;
    }
  }

  asm volatile("s_waitcnt vmcnt(0)" ::: "memory");
  __syncthreads();

  // ---- GEMM1 compute for one BK=64 tile ----
  auto compute = [&](int t) {
    const __bf16* wb = Wb + (t & 1) * 10240;
#pragma unroll
    for (int s = 0; s < 2; ++s) {
      int jb = t * 128 + s * 64 + kg * 16;
      bf16x8 eiv = *(const bf16x8*)(eib + m * 1536 + (jb ^ ((m & 7) << 4)));
      bf16x8 ej0 = *(const bf16x8*)(ejb + (w * 2) * 1536 + jb);
      bf16x8 ej1 = *(const bf16x8*)(ejb + (w * 2 + 1) * 1536 + jb);
      bf16x8 af0, af1;
#pragma unroll
      for (int e = 0; e < 8; ++e) {
        float ei = (float)eiv[e];
        af0[e] = (__bf16)(ei * (float)ej0[e]);
        af1[e] = (__bf16)(ei * (float)ej1[e]);
      }
#pragma unroll
      for (int ct = 0; ct < 10; ++ct) {
        bf16x8 wf = *(const bf16x8*)(wb + (s * 10 + ct) * 512 + l * 8);
        acc[0][ct] = MFMA16(af0, wf, acc[0][ct]);
        acc[1][ct] = MFMA16(af1, wf, acc[1][ct]);
      }
    }
  };

  // ---- main loop: iters 0..10 counted-vmcnt pipelined; t=11 peeled ----
  for (int t = 0; t < 11; ++t) {
#pragma unroll
    for (int q = 0; q < 5; ++q)
      glds16(W1cp + ((size_t)(t + 1) * 20 + w * 5 + q) * 512 + l * 8,
             Wb + (((t + 1) & 1) * 20 + w * 5 + q) * 512);
    asm volatile("s_waitcnt vmcnt(5)\ns_barrier" ::: "memory");
    compute(t);
    asm volatile("s_barrier" ::: "memory");
  }
  asm volatile("s_waitcnt vmcnt(0)\ns_barrier" ::: "memory");
  compute(11);
  asm volatile("s_barrier" ::: "memory");

  // ---- h1 -> LDS (wave-private regions) ----
#pragma unroll
  for (int rr = 0; rr < 4; ++rr)
#pragma unroll
    for (int ct = 0; ct < 10; ++ct) {
      h1r0[(w * 16 + kg * 4 + rr) * 168 + ct * 16 + m] =
          (__bf16)fmaxf(acc[0][ct][rr], 0.f);
      h1r1[(w * 16 + kg * 4 + rr) * 160 + ct * 16 + m] =
          (__bf16)fmaxf(acc[1][ct][rr], 0.f);
    }

  // ---- GEMM2: W2 slice-dbuf in W2b; h2 = h1 @ W2 (5 slices) ----
  for (int f = w; f < 10; f += 4)
    glds16(W2p + (size_t)f * 512 + l * 8, W2b + f * 512);
  asm volatile("s_waitcnt vmcnt(0)" ::: "memory");
  __syncthreads();

  f32x4 acc2[2][10];
#pragma unroll
  for (int rg = 0; rg < 2; ++rg)
#pragma unroll
    for (int u = 0; u < 10; ++u) acc2[rg][u] = (f32x4){0.f, 0.f, 0.f, 0.f};

  for (int s = 0; s < 5; ++s) {
    if (s < 4)
      for (int f = w; f < 10; f += 4)
        glds16(W2p + (size_t)((s + 1) * 10 + f) * 512 + l * 8,
               W2b + ((s + 1) & 1) * 5120 + f * 512);
    bf16x8 a0 = *(const bf16x8*)(h1r0 + (w * 16 + m) * 168 + s * 32 + kg * 8);
    bf16x8 a1 = *(const bf16x8*)(h1r1 + (w * 16 + m) * 160 + s * 32 + kg * 8);
#pragma unroll
    for (int ct = 0; ct < 10; ++ct) {
      bf16x8 wf = *(const bf16x8*)(W2b + (s & 1) * 5120 + ct * 512 + l * 8);
      acc2[0][ct] = MFMA16(a0, wf, acc2[0][ct]);
      acc2[1][ct] = MFMA16(a1, wf, acc2[1][ct]);
    }
    asm volatile("s_waitcnt vmcnt(0)\ns_barrier" ::: "memory");
  }

  // ---- epilogue: s = relu(h2+b2) @ W3 + b3; store valid pairs ----
  float b3v = b3[0];
#pragma unroll
  for (int rg = 0; rg < 2; ++rg) {
    float part[4] = {0.f, 0.f, 0.f, 0.f};
#pragma unroll
    for (int ct = 0; ct < 10; ++ct) {
      int h = ct * 16 + m;
      float bb = (h < 150) ? b2[h] : 0.f;
      float w3 = (h < 150) ? W3[h] : 0.f;
#pragma unroll
      for (int rr = 0; rr < 4; ++rr)
        part[rr] += fmaxf(acc2[rg][ct][rr] + bb, 0.f) * w3;
    }
#pragma unroll
    for (int off = 8; off >= 1; off >>= 1) {
#pragma unroll
      for (int rr = 0; rr < 4; ++rr) part[rr] += __shfl_xor(part[rr], off, 16);
    }
#pragma unroll
    for (int rr = 0; rr < 4; ++rr) {
      if (m == rr) {
        int il = it * 16 + kg * 4 + rr;
        int jl = jt * 8 + w * 2 + rg;
        if (jl < il)
          out[((size_t)(b * NSEQ + il)) * NSEQ + jl] = part[rr] + b3v;
      }
    }
  }
}

// ---------------------------------------------------------------------------
// softmax: 4 (b,i)-rows per block, one wave each.
// ---------------------------------------------------------------------------
__global__ __launch_bounds__(256) void softmax_rows(float* __restrict__ out) {
  int w = threadIdx.x >> 6, l = threadIdx.x & 63;
  int blk = blockIdx.x * 4 + w;   // 0..1535 = b*192+i
  int i = blk % NSEQ;
  size_t base = (size_t)blk * NSEQ;
  float v[3];
  float mx = NEGINF;
#pragma unroll
  for (int t = 0; t < 3; ++t) {
    int j = l + 64 * t;
    float x = (j < i) ? out[base + j] : (j == i ? 0.f : NEGINF);
    v[t] = x;
    mx = fmaxf(mx, x);
  }
#pragma unroll
  for (int off = 32; off >= 1; off >>= 1) mx = fmaxf(mx, __shfl_xor(mx, off, 64));
  float s = 0.f;
#pragma unroll
  for (int t = 0; t < 3; ++t) s += __expf(v[t] - mx);
#pragma unroll
  for (int off = 32; off >= 1; off >>= 1) s += __shfl_xor(s, off, 64);
  float inv = 1.0f / s;
#pragma unroll
  for (int t = 0; t < 3; ++t) {
    int j = l + 64 * t;
    out[base + j] = (j <= i) ? __expf(v[t] - mx) * inv : PADV;
  }
}

// ---------------------------------------------------------------------------
extern "C" void kernel_launch(void* const* d_in, const int* in_sizes, int n_in,
                              void* d_out, int out_size, void* d_ws, size_t ws_size,
                              hipStream_t stream) {
  const float* E  = (const float*)d_in[0];
  const float* W1 = (const float*)d_in[1];
  const float* b1 = (const float*)d_in[2];
  const float* W2 = (const float*)d_in[3];
  const float* b2 = (const float*)d_in[4];
  const float* W3 = (const float*)d_in[5];
  const float* b3 = (const float*)d_in[6];
  float* out = (float*)d_out;

  char* ws = (char*)d_ws;
  float*  A12   = (float*)(ws);                 // 1536*320*4 = 1,966,080 B
  __bf16* W1abp = (__bf16*)(ws + 1966080);      //   491,520 B
  __bf16* W1cp  = (__bf16*)(ws + 2457600);      //   245,760 B
  __bf16* W2p   = (__bf16*)(ws + 2703360);      //    51,200 B

  hipMemsetAsync(A12, 0, 1966080, stream);
  prep_pack<<<1540, 256, 0, stream>>>(W1, W2, W1abp, W1cp, W2p);
  prep_gemm<<<768, 256, 0, stream>>>(E, W1abp, A12);
  pair_mlp<<<1248, 256, 0, stream>>>(E, A12, W1cp, W2p, b1, b2, W3, b3, out);
  softmax_rows<<<384, 256, 0, stream>>>(out);
}